// Round 1
// baseline (533.159 us; speedup 1.0000x reference)
//
#include <hip/hip_runtime.h>
#include <hip/hip_bf16.h>

#define BB 4
#define LL 4096
#define DD 2048
#define HH 8
#define NC 64
#define LC (LL/NC)

typedef __attribute__((ext_vector_type(8))) short short8;
typedef __attribute__((ext_vector_type(4))) float f32x4;
typedef __attribute__((ext_vector_type(2))) float f32x2;

__device__ __forceinline__ float sigmf(float z) { return 1.0f / (1.0f + __expf(-z)); }

// ---------- kernel 0a: x f32 -> bf16 ----------
__global__ void k_cvt_x(const float* __restrict__ x, short* __restrict__ xb) {
    int i = blockIdx.x * blockDim.x + threadIdx.x;   // 0 .. 4194303
    int base = i * 8;
    float4 v0 = *reinterpret_cast<const float4*>(x + base);
    float4 v1 = *reinterpret_cast<const float4*>(x + base + 4);
    float tmp[8] = {v0.x, v0.y, v0.z, v0.w, v1.x, v1.y, v1.z, v1.w};
    short8 o;
    #pragma unroll
    for (int j = 0; j < 8; ++j) {
        __hip_bfloat16 b = __float2bfloat16(tmp[j]);
        o[j] = *reinterpret_cast<short*>(&b);
    }
    *reinterpret_cast<short8*>(xb + base) = o;
}

// ---------- kernel 0b: W [g][h][i][j] f32 -> Wt [g][h][j][i] bf16 ----------
__global__ void k_cvt_w(const float* __restrict__ igw, const float* __restrict__ agw,
                        short* __restrict__ wt) {
    int t = blockIdx.x * blockDim.x + threadIdx.x;   // 0..1048575
    int g = t >> 19;
    int r = t & 524287;
    int h = r >> 16;
    int j = (r >> 8) & 255;
    int i = r & 255;
    const float* src = (g == 0) ? igw : agw;
    float v = src[(h << 16) + (i << 8) + j];
    __hip_bfloat16 b = __float2bfloat16(v);
    wt[t] = *reinterpret_cast<short*>(&b);
}

// ---------- kernel 0c: msp[d] = -8 * softplus(a_param[d]) ----------
__global__ void k_msp(const float* __restrict__ ap, float* __restrict__ msp) {
    int d = blockIdx.x * blockDim.x + threadIdx.x;
    float v = ap[d];
    float sp = (v > 20.f) ? v : log1pf(expf(v));
    msp[d] = -8.0f * sp;
}

// ---------- kernel 1: both gate GEMMs + epilogue -> a (into d_out scratch), nx ----------
__launch_bounds__(256, 2)
__global__ void k_gates(const short* __restrict__ xb, const short* __restrict__ wt,
                        const float* __restrict__ x, const float* __restrict__ msp,
                        const float* __restrict__ igb, const float* __restrict__ agb,
                        float* __restrict__ aout, float* __restrict__ nxout) {
    __shared__ __align__(16) short As[128 * 64];
    __shared__ __align__(16) short Bs[2][128 * 64];

    const int tid  = threadIdx.x;
    const int lane = tid & 63;
    const int w    = tid >> 6;
    const int wr   = w >> 1, wc = w & 1;
    const int mBase = blockIdx.x * 128;
    const int nBase = blockIdx.y * 128;
    const int h     = blockIdx.z;

    f32x4 acc[2][4][4];
    #pragma unroll
    for (int g = 0; g < 2; ++g)
        #pragma unroll
        for (int m = 0; m < 4; ++m)
            #pragma unroll
            for (int n = 0; n < 4; ++n)
                acc[g][m][n] = (f32x4){0.f, 0.f, 0.f, 0.f};

    for (int ks = 0; ks < 4; ++ks) {
        const int kBase = ks * 64;
        __syncthreads();
        // stage A tile [128 rows][64 k] bf16, XOR-swizzled 16B chunks
        #pragma unroll
        for (int i = 0; i < 4; ++i) {
            int cid = tid + (i << 8);
            int r = cid >> 3, c = cid & 7;
            short8 v = *reinterpret_cast<const short8*>(
                xb + (mBase + r) * 2048 + (h << 8) + kBase + (c << 3));
            *reinterpret_cast<short8*>(&As[(r << 6) + (((c ^ (r & 7))) << 3)]) = v;
        }
        // stage B^T tiles [128 j][64 k] for both gates
        #pragma unroll
        for (int g = 0; g < 2; ++g) {
            #pragma unroll
            for (int i = 0; i < 4; ++i) {
                int cid = tid + (i << 8);
                int r = cid >> 3, c = cid & 7;
                short8 v = *reinterpret_cast<const short8*>(
                    wt + ((((g << 3) + h) << 8) + nBase + r) * 256 + kBase + (c << 3));
                *reinterpret_cast<short8*>(&Bs[g][(r << 6) + (((c ^ (r & 7))) << 3)]) = v;
            }
        }
        __syncthreads();
        #pragma unroll
        for (int kk = 0; kk < 2; ++kk) {
            short8 af[4];
            #pragma unroll
            for (int m = 0; m < 4; ++m) {
                int ro = wr * 64 + m * 16 + (lane & 15);
                int ch = ((kk << 2) + (lane >> 4)) ^ (ro & 7);
                af[m] = *reinterpret_cast<const short8*>(&As[(ro << 6) + (ch << 3)]);
            }
            #pragma unroll
            for (int g = 0; g < 2; ++g) {
                #pragma unroll
                for (int n = 0; n < 4; ++n) {
                    int no = wc * 64 + n * 16 + (lane & 15);
                    int ch = ((kk << 2) + (lane >> 4)) ^ (no & 7);
                    short8 bf = *reinterpret_cast<const short8*>(&Bs[g][(no << 6) + (ch << 3)]);
                    #pragma unroll
                    for (int m = 0; m < 4; ++m) {
                        acc[g][m][n] = __builtin_amdgcn_mfma_f32_16x16x32_bf16(
                            af[m], bf, acc[g][m][n], 0, 0, 0);
                    }
                }
            }
        }
    }

    // epilogue: C/D layout col=lane&15, row=(lane>>4)*4+reg
    const int r4 = lane >> 4;
    const int cl = lane & 15;
    #pragma unroll
    for (int m = 0; m < 4; ++m) {
        #pragma unroll
        for (int n = 0; n < 4; ++n) {
            int jc   = nBase + wc * 64 + n * 16 + cl;     // 0..255 within head
            int dcol = (h << 8) + jc;
            float bi = igb[dcol];
            float ba = agb[dcol];
            float ms = msp[dcol];
            #pragma unroll
            for (int r = 0; r < 4; ++r) {
                int p = mBase + wr * 64 + m * 16 + r4 * 4 + r;
                float zi = acc[0][m][n][r] + bi;
                float za = acc[1][m][n][r] + ba;
                float gx = sigmf(zi);
                float ga = sigmf(za);
                float la = ms * ga;
                float av = __expf(la);
                float mult = sqrtf(fmaxf(1.0f - av * av, 0.0f));
                int idx = p * 2048 + dcol;
                float xv = x[idx];
                aout[idx]  = av;
                nxout[idx] = xv * gx * mult;
            }
        }
    }
}

// ---------- kernel 2: per-chunk local scan -> P (prod a), S (local final h) ----------
__global__ void k_scanA(const float* __restrict__ aD, const float* __restrict__ nxD,
                        float* __restrict__ P, float* __restrict__ S) {
    int d2 = blockIdx.x * blockDim.x + threadIdx.x;   // pair index 0..1023
    int c = blockIdx.y, b = blockIdx.z;
    int base = ((b << 12) + c * LC) * 2048 + (d2 << 1);
    float h0 = 0.f, h1 = 0.f, p0 = 1.f, p1 = 1.f;
    #pragma unroll 8
    for (int s = 0; s < LC; ++s) {
        f32x2 av = *reinterpret_cast<const f32x2*>(aD  + base + s * 2048);
        f32x2 nv = *reinterpret_cast<const f32x2*>(nxD + base + s * 2048);
        h0 = fmaf(av[0], h0, nv[0]);
        h1 = fmaf(av[1], h1, nv[1]);
        p0 *= av[0];
        p1 *= av[1];
    }
    int o = ((b * NC + c) << 11) + (d2 << 1);
    f32x2 pp; pp[0] = p0; pp[1] = p1;
    f32x2 ss; ss[0] = h0; ss[1] = h1;
    *reinterpret_cast<f32x2*>(P + o) = pp;
    *reinterpret_cast<f32x2*>(S + o) = ss;
}

// ---------- kernel 3: exclusive prefix over chunks -> H0 ----------
__global__ void k_mid(const float* __restrict__ hs, const float* __restrict__ P,
                      const float* __restrict__ S, float* __restrict__ H0) {
    int t = blockIdx.x * blockDim.x + threadIdx.x;   // 0..8191
    int b = t >> 11, d = t & 2047;
    float h = hs[t];
    for (int c = 0; c < NC; ++c) {
        int o = ((b * NC + c) << 11) + d;
        H0[o] = h;
        h = fmaf(P[o], h, S[o]);
    }
}

// ---------- kernel 4: fix-up scan, write y and h_final ----------
// NOTE: aD aliases y (a was stored in d_out as scratch); per element the read
// at idx happens before the write at idx in the same thread — no __restrict__
// on aD / y.
__global__ void k_scanB(const float* aD, const float* __restrict__ nxD,
                        const float* __restrict__ H0, float* y, float* __restrict__ hf) {
    int d2 = blockIdx.x * blockDim.x + threadIdx.x;
    int c = blockIdx.y, b = blockIdx.z;
    int base = ((b << 12) + c * LC) * 2048 + (d2 << 1);
    int o = ((b * NC + c) << 11) + (d2 << 1);
    f32x2 h = *reinterpret_cast<const f32x2*>(H0 + o);
    float h0 = h[0], h1 = h[1];
    #pragma unroll 8
    for (int s = 0; s < LC; ++s) {
        f32x2 av = *reinterpret_cast<const f32x2*>(aD  + base + s * 2048);
        f32x2 nv = *reinterpret_cast<const f32x2*>(nxD + base + s * 2048);
        h0 = fmaf(av[0], h0, nv[0]);
        h1 = fmaf(av[1], h1, nv[1]);
        f32x2 oo; oo[0] = h0; oo[1] = h1;
        *reinterpret_cast<f32x2*>(y + base + s * 2048) = oo;
    }
    if (c == NC - 1) {
        f32x2 oo; oo[0] = h0; oo[1] = h1;
        *reinterpret_cast<f32x2*>(hf + (b << 11) + (d2 << 1)) = oo;
    }
}

extern "C" void kernel_launch(void* const* d_in, const int* in_sizes, int n_in,
                              void* d_out, int out_size, void* d_ws, size_t ws_size,
                              hipStream_t stream) {
    (void)in_sizes; (void)n_in; (void)out_size; (void)ws_size;
    const float* x   = (const float*)d_in[0];
    const float* hs  = (const float*)d_in[1];
    const float* ap  = (const float*)d_in[2];
    const float* igw = (const float*)d_in[3];
    const float* igb = (const float*)d_in[4];
    const float* agw = (const float*)d_in[5];
    const float* agb = (const float*)d_in[6];

    float* y  = (float*)d_out;
    float* hf = y + 33554432;

    char*  ws  = (char*)d_ws;
    short* xb  = (short*)(ws);                 // 67,108,864 B
    short* wt  = (short*)(ws + 67108864);      //  2,097,152 B
    float* msp = (float*)(ws + 69206016);      //      8,192 B
    float* nx  = (float*)(ws + 69214208);      // 134,217,728 B
    float* P   = (float*)(ws + 203431936);     //  2,097,152 B
    float* S   = (float*)(ws + 205529088);     //  2,097,152 B
    float* H0  = (float*)(ws + 207626240);     //  2,097,152 B
    float* aD  = y;                            // a scratch lives in d_out

    k_cvt_x<<<16384, 256, 0, stream>>>(x, xb);
    k_cvt_w<<<4096, 256, 0, stream>>>(igw, agw, wt);
    k_msp<<<8, 256, 0, stream>>>(ap, msp);
    k_gates<<<dim3(128, 2, 8), 256, 0, stream>>>(xb, wt, x, msp, igb, agb, aD, nx);
    k_scanA<<<dim3(4, NC, BB), 256, 0, stream>>>(aD, nx, P, S);
    k_mid<<<32, 256, 0, stream>>>(hs, P, S, H0);
    k_scanB<<<dim3(4, NC, BB), 256, 0, stream>>>(aD, nx, H0, y, hf);
}

// Round 3
// 448.118 us; speedup vs baseline: 1.1898x; 1.1898x over previous
//
#include <hip/hip_runtime.h>
#include <hip/hip_bf16.h>

#define BB 4
#define LL 4096
#define DD 2048
#define HH 8
#define NC 64
#define LC (LL/NC)

typedef __attribute__((ext_vector_type(8))) short short8;
typedef __attribute__((ext_vector_type(4))) float f32x4;
typedef __attribute__((ext_vector_type(2))) float f32x2;
typedef __attribute__((ext_vector_type(2))) unsigned int u32x2;

__device__ __forceinline__ float sigmf(float z) { return 1.0f / (1.0f + __expf(-z)); }

__device__ __forceinline__ unsigned short bf16bits(float v) {
    __hip_bfloat16 b = __float2bfloat16(v);
    return *reinterpret_cast<unsigned short*>(&b);
}
__device__ __forceinline__ float bitsf(unsigned int u) {
    return *reinterpret_cast<float*>(&u);
}

// ---------- kernel 0a: W [g][h][i][j] f32 -> Wt [g][h][j][i] bf16 ----------
__global__ void k_cvt_w(const float* __restrict__ igw, const float* __restrict__ agw,
                        short* __restrict__ wt) {
    int t = blockIdx.x * blockDim.x + threadIdx.x;   // 0..1048575
    int g = t >> 19;
    int r = t & 524287;
    int h = r >> 16;
    int j = (r >> 8) & 255;
    int i = r & 255;
    const float* src = (g == 0) ? igw : agw;
    float v = src[(h << 16) + (i << 8) + j];
    wt[t] = (short)bf16bits(v);
}

// ---------- kernel 0b: msp2[d] = -8 * softplus(a_param[d]) * log2(e) ----------
__global__ void k_msp(const float* __restrict__ ap, float* __restrict__ msp2) {
    int d = blockIdx.x * blockDim.x + threadIdx.x;
    float v = ap[d];
    float sp = (v > 20.f) ? v : log1pf(expf(v));
    msp2[d] = -8.0f * sp * 1.44269504088896f;
}

// ---------- kernel 1: gate GEMMs + epilogue + fused chunk-scan ----------
// writes packed u32 (hi16 = bf16(log2 a), lo16 = bf16(nx)); P,S per chunk.
__launch_bounds__(256, 2)
__global__ void k_gates(const float* __restrict__ x, const short* __restrict__ wt,
                        const float* __restrict__ msp2,
                        const float* __restrict__ igb, const float* __restrict__ agb,
                        unsigned int* __restrict__ packed,
                        float* __restrict__ P, float* __restrict__ S) {
    __shared__ __align__(16) short As[128 * 64];
    __shared__ __align__(16) short Bs[2][128 * 64];

    const int tid  = threadIdx.x;
    const int lane = tid & 63;
    const int w    = tid >> 6;
    const int wr   = w >> 1, wc = w & 1;
    const int mBase = blockIdx.x * 128;
    const int nBase = blockIdx.y * 128;
    const int h     = blockIdx.z;

    f32x4 acc[2][4][4];
    #pragma unroll
    for (int g = 0; g < 2; ++g)
        #pragma unroll
        for (int m = 0; m < 4; ++m)
            #pragma unroll
            for (int n = 0; n < 4; ++n)
                acc[g][m][n] = (f32x4){0.f, 0.f, 0.f, 0.f};

    for (int ks = 0; ks < 4; ++ks) {
        const int kBase = ks * 64;
        __syncthreads();
        // stage A tile [128 rows][64 k]: read x f32, convert to bf16, XOR-swizzled
        #pragma unroll
        for (int i = 0; i < 4; ++i) {
            int cid = tid + (i << 8);
            int r = cid >> 3, c = cid & 7;
            const float* src = x + (mBase + r) * 2048 + (h << 8) + kBase + (c << 3);
            float4 v0 = *reinterpret_cast<const float4*>(src);
            float4 v1 = *reinterpret_cast<const float4*>(src + 4);
            short8 o;
            o[0] = (short)bf16bits(v0.x); o[1] = (short)bf16bits(v0.y);
            o[2] = (short)bf16bits(v0.z); o[3] = (short)bf16bits(v0.w);
            o[4] = (short)bf16bits(v1.x); o[5] = (short)bf16bits(v1.y);
            o[6] = (short)bf16bits(v1.z); o[7] = (short)bf16bits(v1.w);
            *reinterpret_cast<short8*>(&As[(r << 6) + ((c ^ (r & 7)) << 3)]) = o;
        }
        // stage B^T tiles [128 j][64 k] for both gates (already bf16)
        #pragma unroll
        for (int g = 0; g < 2; ++g) {
            #pragma unroll
            for (int i = 0; i < 4; ++i) {
                int cid = tid + (i << 8);
                int r = cid >> 3, c = cid & 7;
                short8 v = *reinterpret_cast<const short8*>(
                    wt + ((((g << 3) + h) << 8) + nBase + r) * 256 + kBase + (c << 3));
                *reinterpret_cast<short8*>(&Bs[g][(r << 6) + ((c ^ (r & 7)) << 3)]) = v;
            }
        }
        __syncthreads();
        #pragma unroll
        for (int kk = 0; kk < 2; ++kk) {
            short8 af[4];
            #pragma unroll
            for (int m = 0; m < 4; ++m) {
                int ro = wr * 64 + m * 16 + (lane & 15);
                int ch = ((kk << 2) + (lane >> 4)) ^ (ro & 7);
                af[m] = *reinterpret_cast<const short8*>(&As[(ro << 6) + (ch << 3)]);
            }
            #pragma unroll
            for (int g = 0; g < 2; ++g) {
                #pragma unroll
                for (int n = 0; n < 4; ++n) {
                    int no = wc * 64 + n * 16 + (lane & 15);
                    int ch = ((kk << 2) + (lane >> 4)) ^ (no & 7);
                    short8 bf = *reinterpret_cast<const short8*>(&Bs[g][(no << 6) + (ch << 3)]);
                    #pragma unroll
                    for (int m = 0; m < 4; ++m) {
                        acc[g][m][n] = __builtin_amdgcn_mfma_f32_16x16x32_bf16(
                            af[m], bf, acc[g][m][n], 0, 0, 0);
                    }
                }
            }
        }
    }

    // ---- epilogue + fused per-chunk scan ----
    // C/D layout: col = lane&15, row = (lane>>4)*4 + reg.
    // This wave's rows = 64 consecutive time steps = chunk cg.
    const int r4 = lane >> 4;
    const int cl = lane & 15;
    const int cg = blockIdx.x * 2 + wr;      // global chunk id (p/64)

    #pragma unroll
    for (int n = 0; n < 4; ++n) {
        int dcol = (h << 8) + nBase + wc * 64 + n * 16 + cl;
        float bi  = igb[dcol];
        float ba  = agb[dcol];
        float ms2 = msp2[dcol];
        float Am[4], Sm[4];
        #pragma unroll
        for (int m = 0; m < 4; ++m) {
            float Ar = 1.f, Sr = 0.f;
            #pragma unroll
            for (int r = 0; r < 4; ++r) {
                float zi = acc[0][m][n][r] + bi;
                float za = acc[1][m][n][r] + ba;
                float gx = sigmf(zi);
                float ga = sigmf(za);
                float la2 = ms2 * ga;                       // log2(a)
                unsigned int labits = ((unsigned int)bf16bits(la2)) << 16;
                float a = exp2f(bitsf(labits));             // rounded a
                float mult = sqrtf(fmaxf(1.0f - a * a, 0.0f));
                int p = mBase + wr * 64 + m * 16 + r4 * 4 + r;
                float xv = x[p * 2048 + dcol];
                float nx = xv * gx * mult;
                unsigned short nxb = bf16bits(nx);
                packed[p * 2048 + dcol] = labits | (unsigned int)nxb;
                float nxr = bitsf(((unsigned int)nxb) << 16);  // rounded nx
                // ordered combine with element (a, nxr)
                Sr = fmaf(a, Sr, nxr);
                Ar *= a;
            }
            Am[m] = Ar; Sm[m] = Sr;
        }
        // cross-lane ordered combine over r4 groups (lane bits 4,5)
        #pragma unroll
        for (int st = 0; st < 2; ++st) {
            int msk = 16 << st;
            #pragma unroll
            for (int m = 0; m < 4; ++m) {
                float Ap = __shfl_xor(Am[m], msk, 64);
                float Sp = __shfl_xor(Sm[m], msk, 64);
                if (lane & msk) Sm[m] = fmaf(Am[m], Sp, Sm[m]);  // partner earlier
                else            Sm[m] = fmaf(Ap, Sm[m], Sp);      // I am earlier
                Am[m] *= Ap;
            }
        }
        // combine the 4 m-blocks in time order
        float Ac = Am[0], Sc = Sm[0];
        #pragma unroll
        for (int m = 1; m < 4; ++m) { Sc = fmaf(Am[m], Sc, Sm[m]); Ac *= Am[m]; }
        if (r4 == 0) {
            P[cg * 2048 + dcol] = Ac;
            S[cg * 2048 + dcol] = Sc;
        }
    }
}

// ---------- kernel 2: exclusive prefix over chunks -> H0 ----------
__global__ void k_mid(const float* __restrict__ hs, const float* __restrict__ P,
                      const float* __restrict__ S, float* __restrict__ H0) {
    int t = blockIdx.x * blockDim.x + threadIdx.x;   // 0..8191
    int b = t >> 11, d = t & 2047;
    float h = hs[t];
    for (int c = 0; c < NC; ++c) {
        int o = ((b * NC + c) << 11) + d;
        H0[o] = h;
        h = fmaf(P[o], h, S[o]);
    }
}

// ---------- kernel 3: fix-up scan, write y and h_final ----------
__global__ void k_scanB(const unsigned int* __restrict__ pk,
                        const float* __restrict__ H0,
                        float* __restrict__ y, float* __restrict__ hf) {
    int d2 = blockIdx.x * blockDim.x + threadIdx.x;  // pair index 0..1023
    int c = blockIdx.y, b = blockIdx.z;
    int base = ((b << 12) + c * LC) * 2048 + (d2 << 1);
    int o = ((b * NC + c) << 11) + (d2 << 1);
    f32x2 h = *reinterpret_cast<const f32x2*>(H0 + o);
    float h0 = h[0], h1 = h[1];
    #pragma unroll 8
    for (int s = 0; s < LC; ++s) {
        u32x2 wv = *reinterpret_cast<const u32x2*>(pk + base + s * 2048);
        float a0  = exp2f(bitsf(wv[0] & 0xFFFF0000u));
        float nx0 = bitsf(wv[0] << 16);
        float a1  = exp2f(bitsf(wv[1] & 0xFFFF0000u));
        float nx1 = bitsf(wv[1] << 16);
        h0 = fmaf(a0, h0, nx0);
        h1 = fmaf(a1, h1, nx1);
        f32x2 oo; oo[0] = h0; oo[1] = h1;
        *reinterpret_cast<f32x2*>(y + base + s * 2048) = oo;
    }
    if (c == NC - 1) {
        f32x2 oo; oo[0] = h0; oo[1] = h1;
        *reinterpret_cast<f32x2*>(hf + (b << 11) + (d2 << 1)) = oo;
    }
}

extern "C" void kernel_launch(void* const* d_in, const int* in_sizes, int n_in,
                              void* d_out, int out_size, void* d_ws, size_t ws_size,
                              hipStream_t stream) {
    (void)in_sizes; (void)n_in; (void)out_size; (void)ws_size;
    const float* x   = (const float*)d_in[0];
    const float* hs  = (const float*)d_in[1];
    const float* ap  = (const float*)d_in[2];
    const float* igw = (const float*)d_in[3];
    const float* igb = (const float*)d_in[4];
    const float* agw = (const float*)d_in[5];
    const float* agb = (const float*)d_in[6];

    float* y  = (float*)d_out;
    float* hf = y + 33554432;

    // pk is B*L*D u32 = 134,217,728 B (Round-2 bug: was sized 67 MB and
    // overlapped P/S/H0 -> NaN). Total ws use: 142,614,528 B.
    char*         ws   = (char*)d_ws;
    short*        wt   = (short*)(ws);                     //   2,097,152 B
    float*        msp2 = (float*)(ws + 2097152);           //       8,192 B
    unsigned int* pk   = (unsigned int*)(ws + 2105344);    // 134,217,728 B
    float*        P    = (float*)(ws + 136323072);         //   2,097,152 B
    float*        S    = (float*)(ws + 138420224);         //   2,097,152 B
    float*        H0   = (float*)(ws + 140517376);         //   2,097,152 B

    k_cvt_w<<<4096, 256, 0, stream>>>(igw, agw, wt);
    k_msp<<<8, 256, 0, stream>>>(ap, msp2);
    k_gates<<<dim3(128, 2, 8), 256, 0, stream>>>(x, wt, msp2, igb, agb, pk, P, S);
    k_mid<<<32, 256, 0, stream>>>(hs, P, S, H0);
    k_scanB<<<dim3(4, NC, BB), 256, 0, stream>>>(pk, H0, y, hf);
}